// Round 6
// baseline (746.522 us; speedup 1.0000x reference)
//
#include <hip/hip_runtime.h>

// MonotoneiResBlock: B=131072 rows, D=64, H=256.
//   forward:  w <- sqrt2*x - tanh(w@W1)@W2   (10 iters; Lip~0.49)
//   y = sqrt2*w - x = x - sqrt2*g_last
//   logdet = -2 * sum_{k odd<=9} eps^T J^k eps,   J v = (sech^2(w@W1) o (v@W1)) @ W2
// Transposed MFMA GEMMs, shared K-permutation pi so GEMM1's D-frag feeds GEMM2 as B-frag.
// Round-6: kill the spill (rounds 2-5 all scratch-bound; LLVM capped VGPR at 128 because 64KB LDS
// implied a 2-block/CU occupancy target):
//   - amdgpu_waves_per_eu(1,2) + LDS padded to 96KB -> 1 block/CU target -> 256-VGPR budget
//   - scalar-p Neumann (no s/tt arrays), only sx + w-frags live in fwd loop
// d_out FLOAT32: y = 131072*64, then logdet = 131072.

typedef __attribute__((ext_vector_type(8))) short bf16x8;
typedef __attribute__((ext_vector_type(4))) float f32x4;
typedef __attribute__((ext_vector_type(4))) unsigned int u32x4;

#define SQRT2F 1.41421356237309515f
#define INVSQRT2F 0.70710678118654752f
#define NITER 10

__device__ __forceinline__ unsigned int pack2(float a, float b) {
    unsigned int ua = __builtin_bit_cast(unsigned int, a);
    unsigned int ub = __builtin_bit_cast(unsigned int, b);
    return ((ua + 0x8000u) >> 16) | ((ub + 0x8000u) & 0xFFFF0000u);
}
__device__ __forceinline__ float bf_lo(unsigned int u) { return __builtin_bit_cast(float, u << 16); }
__device__ __forceinline__ float bf_hi(unsigned int u) { return __builtin_bit_cast(float, u & 0xFFFF0000u); }
__device__ __forceinline__ float fast_tanh(float xx) {
    float a = __expf(xx + xx);
    float r = __builtin_amdgcn_rcpf(a + 1.0f);
    return fmaf(-2.0f, r, 1.0f);
}
__device__ __forceinline__ bf16x8 packfrag4(f32x4 a, f32x4 b) {
    u32x4 r;
    r[0] = pack2(a[0], a[1]); r[1] = pack2(a[2], a[3]);
    r[2] = pack2(b[0], b[1]); r[3] = pack2(b[2], b[3]);
    return __builtin_bit_cast(bf16x8, r);
}

// Fused pass over 32 rows (two 16-row groups share every weight A-frag ds_read).
// MODE 0: tanh. MODE 1: tanh + capture dd, skip GEMM2 (g untouched). MODE 2: dd-multiply.
template <int MODE>
__device__ __forceinline__ void fused_pass32(const u32x4* __restrict__ sW1p, const u32x4* __restrict__ sW2p,
                                             int lane, bf16x8 b00, bf16x8 b01, bf16x8 b10, bf16x8 b11,
                                             unsigned int (&dpk)[2][16][2], f32x4 (&g)[2][4]) {
    f32x4 zz = {0.f, 0.f, 0.f, 0.f};
    if constexpr (MODE != 1) {
#pragma unroll
        for (int gi = 0; gi < 2; ++gi)
#pragma unroll
            for (int t = 0; t < 4; ++t) g[gi][t] = zz;
    }
#pragma unroll
    for (int kk = 0; kk < 8; ++kk) {
        u32x4 hbk0, hbk1;
#pragma unroll
        for (int sub = 0; sub < 2; ++sub) {
            const int m = 2 * kk + sub;
            u32x4 wA = sW1p[(m * 2 + 0) * 64 + lane];
            u32x4 wB = sW1p[(m * 2 + 1) * 64 + lane];
            f32x4 a0 = zz, a1 = zz;
            a0 = __builtin_amdgcn_mfma_f32_16x16x32_bf16(__builtin_bit_cast(bf16x8, wA), b00, a0, 0, 0, 0);
            a0 = __builtin_amdgcn_mfma_f32_16x16x32_bf16(__builtin_bit_cast(bf16x8, wB), b01, a0, 0, 0, 0);
            a1 = __builtin_amdgcn_mfma_f32_16x16x32_bf16(__builtin_bit_cast(bf16x8, wA), b10, a1, 0, 0, 0);
            a1 = __builtin_amdgcn_mfma_f32_16x16x32_bf16(__builtin_bit_cast(bf16x8, wB), b11, a1, 0, 0, 0);
            float h00, h01, h02, h03, h10, h11, h12, h13;
            if constexpr (MODE == 2) {
                h00 = a0[0] * bf_lo(dpk[0][m][0]);
                h01 = a0[1] * bf_hi(dpk[0][m][0]);
                h02 = a0[2] * bf_lo(dpk[0][m][1]);
                h03 = a0[3] * bf_hi(dpk[0][m][1]);
                h10 = a1[0] * bf_lo(dpk[1][m][0]);
                h11 = a1[1] * bf_hi(dpk[1][m][0]);
                h12 = a1[2] * bf_lo(dpk[1][m][1]);
                h13 = a1[3] * bf_hi(dpk[1][m][1]);
            } else {
                h00 = fast_tanh(a0[0]); h01 = fast_tanh(a0[1]);
                h02 = fast_tanh(a0[2]); h03 = fast_tanh(a0[3]);
                h10 = fast_tanh(a1[0]); h11 = fast_tanh(a1[1]);
                h12 = fast_tanh(a1[2]); h13 = fast_tanh(a1[3]);
                if constexpr (MODE == 1) {
                    dpk[0][m][0] = pack2(fmaf(-h00, h00, 1.0f), fmaf(-h01, h01, 1.0f));
                    dpk[0][m][1] = pack2(fmaf(-h02, h02, 1.0f), fmaf(-h03, h03, 1.0f));
                    dpk[1][m][0] = pack2(fmaf(-h10, h10, 1.0f), fmaf(-h11, h11, 1.0f));
                    dpk[1][m][1] = pack2(fmaf(-h12, h12, 1.0f), fmaf(-h13, h13, 1.0f));
                }
            }
            if constexpr (MODE != 1) {
                hbk0[2 * sub + 0] = pack2(h00, h01); hbk0[2 * sub + 1] = pack2(h02, h03);
                hbk1[2 * sub + 0] = pack2(h10, h11); hbk1[2 * sub + 1] = pack2(h12, h13);
            }
        }
        if constexpr (MODE != 1) {
            bf16x8 bh0 = __builtin_bit_cast(bf16x8, hbk0);
            bf16x8 bh1 = __builtin_bit_cast(bf16x8, hbk1);
#pragma unroll
            for (int t = 0; t < 4; ++t) {
                bf16x8 w2 = __builtin_bit_cast(bf16x8, sW2p[(t * 8 + kk) * 64 + lane]);
                g[0][t] = __builtin_amdgcn_mfma_f32_16x16x32_bf16(w2, bh0, g[0][t], 0, 0, 0);
                g[1][t] = __builtin_amdgcn_mfma_f32_16x16x32_bf16(w2, bh1, g[1][t], 0, 0, 0);
            }
        }
    }
}

__global__ __launch_bounds__(512) __attribute__((amdgpu_waves_per_eu(1, 2)))
void monot_kernel(
    const float* __restrict__ x, const float* __restrict__ eps,
    const float* __restrict__ W1, const float* __restrict__ W2,
    float* __restrict__ out) {
    __shared__ u32x4 sW1p[2048];  // [m0(16)][kk(2)][lane(64)] A-frags of W1^T, pi-permuted K
    __shared__ u32x4 sW2p[4096];  // lower 2048: [m0(4)][kk(8)][lane(64)] A-frags of W2^T;
                                  // upper 2048: occupancy pad -> 96KB LDS -> 1-block/CU reg target

    const int tid = threadIdx.x;
    const int lane = tid & 63;
    const int wv = tid >> 6;
    const int c = lane & 15;
    const int q = lane >> 4;

    // ---- pack weights into LDS (A-frag layout; pi(q,j) = 4q + (j&3) + 16*(j>>2)) ----
#pragma unroll
    for (int e0 = 0; e0 < 4; ++e0) {
        int idx = e0 * 512 + tid;  // W1 entries
        int l = idx & 63;
        int lq = l >> 4, lc = l & 15;
        int m0 = idx >> 7;
        int kk = (idx >> 6) & 1;
        float v[8];
#pragma unroll
        for (int j = 0; j < 8; ++j) {
            int kp = 32 * kk + 4 * lq + (j & 3) + ((j >> 2) << 4);
            v[j] = W1[kp * 256 + 16 * m0 + lc];  // W1^T[16m0+lc][kp]
        }
        u32x4 pk;
        pk[0] = pack2(v[0], v[1]); pk[1] = pack2(v[2], v[3]);
        pk[2] = pack2(v[4], v[5]); pk[3] = pack2(v[6], v[7]);
        sW1p[idx] = pk;
    }
#pragma unroll
    for (int e0 = 0; e0 < 4; ++e0) {
        int idx = e0 * 512 + tid;  // W2 entries
        int l = idx & 63;
        int lq = l >> 4, lc = l & 15;
        int m0 = idx >> 9;
        int kk = (idx >> 6) & 7;
        float v[8];
#pragma unroll
        for (int j = 0; j < 8; ++j) {
            int kp = 32 * kk + 4 * lq + (j & 3) + ((j >> 2) << 4);
            v[j] = W2[kp * 64 + 16 * m0 + lc];  // W2^T[16m0+lc][kp]
        }
        u32x4 pk;
        pk[0] = pack2(v[0], v[1]); pk[1] = pack2(v[2], v[3]);
        pk[2] = pack2(v[4], v[5]); pk[3] = pack2(v[6], v[7]);
        sW2p[idx] = pk;
    }
    __syncthreads();

    // wave handles 32 rows: group0 = lane c, group1 = +16 rows
    const int row0 = blockIdx.x * 256 + wv * 32 + c;
    const float* xr0 = x + (size_t)row0 * 64;
    const float* xr1 = xr0 + 16 * 64;

    unsigned int dpk[2][16][2];  // dd packed bf16 per group (filled by MODE-1 pass)
    f32x4 sx[2][4];              // sqrt2 * x, lane dims 16m+4q+r
    bf16x8 b00, b01, b10, b11;   // bf16 frags of current w
    {
        f32x4 t00 = *(const f32x4*)(xr0 + 0 + 4 * q);
        f32x4 t01 = *(const f32x4*)(xr0 + 16 + 4 * q);
        f32x4 t02 = *(const f32x4*)(xr0 + 32 + 4 * q);
        f32x4 t03 = *(const f32x4*)(xr0 + 48 + 4 * q);
        f32x4 t10 = *(const f32x4*)(xr1 + 0 + 4 * q);
        f32x4 t11 = *(const f32x4*)(xr1 + 16 + 4 * q);
        f32x4 t12 = *(const f32x4*)(xr1 + 32 + 4 * q);
        f32x4 t13 = *(const f32x4*)(xr1 + 48 + 4 * q);
#pragma unroll
        for (int r = 0; r < 4; ++r) {
            sx[0][0][r] = SQRT2F * t00[r]; sx[0][1][r] = SQRT2F * t01[r];
            sx[0][2][r] = SQRT2F * t02[r]; sx[0][3][r] = SQRT2F * t03[r];
            sx[1][0][r] = SQRT2F * t10[r]; sx[1][1][r] = SQRT2F * t11[r];
            sx[1][2][r] = SQRT2F * t12[r]; sx[1][3][r] = SQRT2F * t13[r];
        }
        b00 = packfrag4(sx[0][0], sx[0][1]); b01 = packfrag4(sx[0][2], sx[0][3]);
        b10 = packfrag4(sx[1][0], sx[1][1]); b11 = packfrag4(sx[1][2], sx[1][3]);
    }

    f32x4 g[2][4];
    // ---- fixed-point iterations: w_next = sx - g(w); frags hold w ----
#pragma unroll 1
    for (int it = 0; it < NITER; ++it) {
        fused_pass32<0>(sW1p, sW2p, lane, b00, b01, b10, b11, dpk, g);
        f32x4 w00 = sx[0][0] - g[0][0], w01 = sx[0][1] - g[0][1];
        f32x4 w02 = sx[0][2] - g[0][2], w03 = sx[0][3] - g[0][3];
        f32x4 w10 = sx[1][0] - g[1][0], w11 = sx[1][1] - g[1][1];
        f32x4 w12 = sx[1][2] - g[1][2], w13 = sx[1][3] - g[1][3];
        b00 = packfrag4(w00, w01); b01 = packfrag4(w02, w03);
        b10 = packfrag4(w10, w11); b11 = packfrag4(w12, w13);
    }

    // ---- y = x - sqrt2*g_last = inv_sqrt2*sx - sqrt2*g ----
#pragma unroll
    for (int m = 0; m < 4; ++m) {
        f32x4 y0, y1;
#pragma unroll
        for (int r = 0; r < 4; ++r) {
            y0[r] = fmaf(INVSQRT2F, sx[0][m][r], -SQRT2F * g[0][m][r]);
            y1[r] = fmaf(INVSQRT2F, sx[1][m][r], -SQRT2F * g[1][m][r]);
        }
        *(f32x4*)(out + (size_t)row0 * 64 + 16 * m + 4 * q) = y0;
        *(f32x4*)(out + (size_t)(row0 + 16) * 64 + 16 * m + 4 * q) = y1;
    }

    // ---- dd = sech^2(w_final @ W1); frags already hold w_final ----
    fused_pass32<1>(sW1p, sW2p, lane, b00, b01, b10, b11, dpk, g);

    // ---- Neumann: p = sum_{k odd<=9} eps.(J^k eps); logdet = -2p ----
    f32x4 ew[2][4];
    {
        const float* er0 = eps + (size_t)row0 * 64;
        const float* er1 = er0 + 16 * 64;
#pragma unroll
        for (int m = 0; m < 4; ++m) {
            ew[0][m] = *(const f32x4*)(er0 + 16 * m + 4 * q);
            ew[1][m] = *(const f32x4*)(er1 + 16 * m + 4 * q);
        }
    }
    b00 = packfrag4(ew[0][0], ew[0][1]); b01 = packfrag4(ew[0][2], ew[0][3]);
    b10 = packfrag4(ew[1][0], ew[1][1]); b11 = packfrag4(ew[1][2], ew[1][3]);
    float p0 = 0.f, p1 = 0.f;
#pragma unroll 1
    for (int k = 1; k <= 9; ++k) {
        fused_pass32<2>(sW1p, sW2p, lane, b00, b01, b10, b11, dpk, g);
        if (k & 1) {
#pragma unroll
            for (int m = 0; m < 4; ++m)
#pragma unroll
                for (int r = 0; r < 4; ++r) {
                    p0 = fmaf(ew[0][m][r], g[0][m][r], p0);
                    p1 = fmaf(ew[1][m][r], g[1][m][r], p1);
                }
        }
        b00 = packfrag4(g[0][0], g[0][1]); b01 = packfrag4(g[0][2], g[0][3]);
        b10 = packfrag4(g[1][0], g[1][1]); b11 = packfrag4(g[1][2], g[1][3]);
    }
    p0 += __shfl_xor(p0, 16); p0 += __shfl_xor(p0, 32);
    p1 += __shfl_xor(p1, 16); p1 += __shfl_xor(p1, 32);
    p0 *= -2.0f; p1 *= -2.0f;
    if (lane < 16) {
        out[(size_t)8388608 + row0] = p0;
        out[(size_t)8388608 + row0 + 16] = p1;
    }
}

extern "C" void kernel_launch(void* const* d_in, const int* in_sizes, int n_in,
                              void* d_out, int out_size, void* d_ws, size_t ws_size,
                              hipStream_t stream) {
    const float* x = (const float*)d_in[0];
    const float* eps = (const float*)d_in[1];
    const float* W1 = (const float*)d_in[2];
    const float* W2 = (const float*)d_in[3];
    float* out = (float*)d_out;
    // 131072 rows / (8 waves * 32 rows) = 512 blocks
    monot_kernel<<<dim3(512), dim3(512), 0, stream>>>(x, eps, W1, W2, out);
}